// Round 8
// baseline (5976.932 us; speedup 1.0000x reference)
//
#include <hip/hip_runtime.h>

#define LNUM 8
#define WD 128
#define BATCH 262144
#define BLK 512

typedef unsigned int u32;
typedef __attribute__((ext_vector_type(8))) short bf16x8;
typedef __attribute__((ext_vector_type(4))) float f32x4;

// packed f32x2 -> bf16x2 (single VALU op)
__device__ __forceinline__ u32 pk2(float x, float y){
  u32 r;
  asm("v_cvt_pk_bf16_f32 %0, %1, %2" : "=v"(r) : "v"(x), "v"(y));
  return r;
}

// Stage a 128x128 fp32 weight matrix into LDS as bf16, row-major, XOR-swizzled
// (4-dword granularity: dword ^ ((row&7)<<2)). 512 threads: row j=t>>2, quarter q=t&3.
__device__ __forceinline__ void stage_W(const float* __restrict__ src, u32* dst, int tid){
  const int j = tid >> 2, q = tid & 3;
  const float* s = src + j * WD + q * 32;
  u32* drow = dst + j * 64;
  const int base = q * 16;
  const u32 sz = (u32)((j & 7) << 2);
#pragma unroll
  for(int c = 0; c < 4; ++c){
    float4 f0 = *(const float4*)(s + c * 8);
    float4 f1 = *(const float4*)(s + c * 8 + 4);
    uint4 w;
    w.x = pk2(f0.x, f0.y); w.y = pk2(f0.z, f0.w);
    w.z = pk2(f1.x, f1.y); w.w = pk2(f1.z, f1.w);
    *(uint4*)(drow + (((u32)(base + c * 4)) ^ sz)) = w;
  }
}

// Whole 4-stage MLP for the wave's 64 samples via 4 quarter-passes (16 samples).
// Returns own-sample pre-activation (before +b4, tanh).
//
// stage1 (NEW): one sparse MFMA per j-tile. A[j,k] = {k=0: W1[j], k=1: b1[j]},
//   natural k-map slot(lg,e)->k=lg*8+e -> nonzero only dword0 of lg==0 lanes.
//   B[s,k] = {k=0: u[s], k=1: 1.0} likewise. D[j,s] = W1[j]*u[s]+b1[j].
// mid1/mid2: permuted k-map slot(lg,e)->k=kt*32+(e>>2)*16+lg*4+(e&3):
//   B = lane's OWN tr dwords (zero cross-lane), A = W row as 2x ds_read_b64 at
//   dwords (kt*16+2lg)^sz and (+8)^sz. Pattern HW-validated R4-R7 (mid2).
// Accumulators bias-initialized via MFMA C-input (validated R7).
__device__ __forceinline__ float mlp_full(
    float u, const u32* __restrict__ W2lds, const u32* __restrict__ W3lds,
    const float* __restrict__ W1, const float* __restrict__ b1,
    const float* __restrict__ b2, const float* __restrict__ b3,
    const float* __restrict__ W4, int lm, int lg)
{
  const f32x4 zero = {0.f, 0.f, 0.f, 0.f};

  // stage-1 A-fragments (8 dwords, live whole MLP)
  u32 A1w[8];
#pragma unroll
  for(int jt = 0; jt < 8; ++jt){
    const int j = lm + 16 * jt;
    const u32 v = pk2(W1[j], b1[j]);
    A1w[jt] = (lg == 0) ? v : 0u;
  }

  float pre = 0.f;

#pragma unroll
  for(int p = 0; p < 4; ++p){
    const float us = __shfl(u, p * 16 + lm, 64);
    const u32 bx = pk2(us, 1.0f);
    uint4 b1v; b1v.x = (lg == 0) ? bx : 0u; b1v.y = 0u; b1v.z = 0u; b1v.w = 0u;
    const bf16x8 bv1 = __builtin_bit_cast(bf16x8, b1v);

    // ---- stage1: 8 sparse MFMAs -> tr1 (H1 in permuted-k layout) ----
    u32 tr1[8][2];
#pragma unroll
    for(int jt = 0; jt < 8; ++jt){
      uint4 a4; a4.x = A1w[jt]; a4.y = 0u; a4.z = 0u; a4.w = 0u;
      f32x4 d = __builtin_amdgcn_mfma_f32_16x16x32_bf16(
          __builtin_bit_cast(bf16x8, a4), bv1, zero, 0, 0, 0);
      tr1[jt][0] = pk2(fmaxf(d[0], 0.f), fmaxf(d[1], 0.f));
      tr1[jt][1] = pk2(fmaxf(d[2], 0.f), fmaxf(d[3], 0.f));
    }

    // ---- mid1: A = W2 (2x b64, permuted), B = own tr1; C-init = b2 ----
    u32 tr2[8][2];
#pragma unroll
    for(int jt = 0; jt < 8; ++jt){
      const int j = lm + 16 * jt;
      const u32 sz = (u32)((j & 7) << 2);
      const u32* r = W2lds + j * 64;
      const float4 bb = *(const float4*)(b2 + jt * 16 + lg * 4);
      f32x4 a = {bb.x, bb.y, bb.z, bb.w};
#pragma unroll
      for(int kt = 0; kt < 4; ++kt){
        const u32 o1 = (u32)(kt * 16 + 2 * lg);
        uint2 lo = *(const uint2*)(r + (o1 ^ sz));
        uint2 hi = *(const uint2*)(r + ((o1 + 8) ^ sz));
        uint4 a4; a4.x = lo.x; a4.y = lo.y; a4.z = hi.x; a4.w = hi.y;
        uint4 q4; q4.x = tr1[2*kt][0]; q4.y = tr1[2*kt][1];
        q4.z = tr1[2*kt+1][0]; q4.w = tr1[2*kt+1][1];
        a = __builtin_amdgcn_mfma_f32_16x16x32_bf16(
            __builtin_bit_cast(bf16x8, a4), __builtin_bit_cast(bf16x8, q4), a, 0, 0, 0);
      }
      tr2[jt][0] = pk2(fmaxf(a[0], 0.f), fmaxf(a[1], 0.f));
      tr2[jt][1] = pk2(fmaxf(a[2], 0.f), fmaxf(a[3], 0.f));
    }

    // ---- mid2 + stage-4 fold: A = W3 (permuted), B = own tr2; C-init = b3 ----
    float p0 = 0.f;
#pragma unroll
    for(int jt = 0; jt < 8; ++jt){
      const int j = lm + 16 * jt;
      const u32 sz = (u32)((j & 7) << 2);
      const u32* r = W3lds + j * 64;
      const float4 bc = *(const float4*)(b3 + jt * 16 + lg * 4);
      f32x4 a = {bc.x, bc.y, bc.z, bc.w};
#pragma unroll
      for(int kt = 0; kt < 4; ++kt){
        const u32 o1 = (u32)(kt * 16 + 2 * lg);
        uint2 lo = *(const uint2*)(r + (o1 ^ sz));
        uint2 hi = *(const uint2*)(r + ((o1 + 8) ^ sz));
        uint4 a4; a4.x = lo.x; a4.y = lo.y; a4.z = hi.x; a4.w = hi.y;
        uint4 q4; q4.x = tr2[2*kt][0]; q4.y = tr2[2*kt][1];
        q4.z = tr2[2*kt+1][0]; q4.w = tr2[2*kt+1][1];
        a = __builtin_amdgcn_mfma_f32_16x16x32_bf16(
            __builtin_bit_cast(bf16x8, a4), __builtin_bit_cast(bf16x8, q4), a, 0, 0, 0);
      }
      const float4 wc = *(const float4*)(W4 + jt * 16 + lg * 4);
      p0 = fmaf(fmaxf(a[0], 0.f), wc.x, p0);
      p0 = fmaf(fmaxf(a[1], 0.f), wc.y, p0);
      p0 = fmaf(fmaxf(a[2], 0.f), wc.z, p0);
      p0 = fmaf(fmaxf(a[3], 0.f), wc.w, p0);
    }
    p0 += __shfl_xor(p0, 16, 64);
    p0 += __shfl_xor(p0, 32, 64);
    if(lg == p) pre = p0;    // own sample (lane lg*16+lm) lives in pass p==lg, col lm
  }
  return pre;
}

extern "C" __global__ void __launch_bounds__(BLK, 4)
flow_kernel(const float* __restrict__ x, const float* __restrict__ s_scale,
            const float* __restrict__ sW1, const float* __restrict__ sb1,
            const float* __restrict__ sW2, const float* __restrict__ sb2,
            const float* __restrict__ sW3, const float* __restrict__ sb3,
            const float* __restrict__ sW4, const float* __restrict__ sb4,
            const float* __restrict__ tW1, const float* __restrict__ tb1,
            const float* __restrict__ tW2, const float* __restrict__ tb2,
            const float* __restrict__ tW3, const float* __restrict__ tb3,
            const float* __restrict__ tW4, const float* __restrict__ tb4,
            float* __restrict__ out)
{
  __shared__ u32 Wlds[2][8192];   // 64 KB: W2 / W3 bf16, swizzled

  const int tid = threadIdx.x;
  const int lane = tid & 63, lg = lane >> 4, lm = lane & 15;
  const int gs = (int)blockIdx.x * BLK + tid;   // this thread's sample

  float2 ab = ((const float2*)x)[gs];
  float* scat = out + 2 * BATCH;

#pragma unroll 1
  for(int i = 0; i < LNUM; ++i){
    const int parity = i & 1;
    const float sc = s_scale[i];
    const int off = i * WD, offW = i * (WD * WD);

    // ---------- phase A: s-MLP ----------
    __syncthreads();                       // previous phase done reading Wlds
    stage_W(sW2 + offW, Wlds[0], tid);
    stage_W(sW3 + offW, Wlds[1], tid);
    __syncthreads();
    const float u = parity ? ab.y : ab.x;
    float preS = mlp_full(u, Wlds[0], Wlds[1], sW1 + off, sb1 + off,
                          sb2 + off, sb3 + off, sW4 + off, lm, lg) + sb4[i];
    const float sv = sc * tanhf(preS);
    scat[i * BATCH + gs] = sv;

    // ---------- phase B: t-MLP + coupling ----------
    __syncthreads();
    stage_W(tW2 + offW, Wlds[0], tid);
    stage_W(tW3 + offW, Wlds[1], tid);
    __syncthreads();
    float preT = mlp_full(u, Wlds[0], Wlds[1], tW1 + off, tb1 + off,
                          tb2 + off, tb3 + off, tW4 + off, lm, lg) + tb4[i];
    const float tv = tanhf(preT);
    const float e = expf(sv);
    if(parity) ab.x = e * ab.x + tv; else ab.y = e * ab.y + tv;
  }

  ((float2*)out)[gs] = ab;
}

extern "C" void kernel_launch(void* const* d_in, const int* in_sizes, int n_in,
                              void* d_out, int out_size, void* d_ws, size_t ws_size,
                              hipStream_t stream) {
  (void)in_sizes; (void)n_in; (void)d_ws; (void)ws_size; (void)out_size;
  const float* p[18];
  for(int k = 0; k < 18; ++k) p[k] = (const float*)d_in[k];
  dim3 grid(BATCH / BLK), block(BLK);
  hipLaunchKernelGGL(flow_kernel, grid, block, 0, stream,
                     p[0], p[1], p[2], p[3], p[4], p[5], p[6], p[7], p[8], p[9],
                     p[10], p[11], p[12], p[13], p[14], p[15], p[16], p[17],
                     (float*)d_out);
}

// Round 9
// 1086.376 us; speedup vs baseline: 5.5017x; 5.5017x over previous
//
#include <hip/hip_runtime.h>

#define LNUM 8
#define WD 128
#define BATCH 262144
#define BLK 256

typedef unsigned int u32;
typedef __attribute__((ext_vector_type(8))) short bf16x8;
typedef __attribute__((ext_vector_type(4))) float f32x4;

// packed f32x2 -> bf16x2 (single VALU op)
__device__ __forceinline__ u32 pk2(float x, float y){
  u32 r;
  asm("v_cvt_pk_bf16_f32 %0, %1, %2" : "=v"(r) : "v"(x), "v"(y));
  return r;
}

// Stage a 128x128 fp32 weight matrix into LDS as bf16, XOR-swizzled, in
// FRAGMENT-CONTIGUOUS permuted order: within each row's kt-chunk (16 dwords),
// dest dwords [lg*4 .. lg*4+3] = original dwords {2lg, 2lg+1, 8+2lg, 8+2lg+1}
// (= elements {4lg..4lg+3} and {16+4lg..16+4lg+3}). A mid-stage A-fragment for
// (lg, kt) under the permuted k-map  slot(lg,e) <-> k = kt*32+(e>>2)*16+lg*4+(e&3)
// is then ONE b128 at dword (kt*16+lg*4)^sz. 256 threads: row j=t>>1, half h=t&1
// (kt-chunks 2h, 2h+1).
__device__ __forceinline__ void stage_W(const float* __restrict__ src, u32* dst, int tid){
  const int j = tid >> 1, h = tid & 1;
  const float* srow = src + j * WD;
  u32* drow = dst + j * 64;
  const u32 sz = (u32)((j & 7) << 2);
#pragma unroll
  for(int kk = 0; kk < 2; ++kk){
    const int kt = 2 * h + kk;
#pragma unroll
    for(int lg = 0; lg < 4; ++lg){
      float4 f0 = *(const float4*)(srow + kt * 32 + lg * 4);
      float4 f1 = *(const float4*)(srow + kt * 32 + 16 + lg * 4);
      uint4 w;
      w.x = pk2(f0.x, f0.y); w.y = pk2(f0.z, f0.w);
      w.z = pk2(f1.x, f1.y); w.w = pk2(f1.z, f1.w);
      *(uint4*)(drow + (((u32)(kt * 16 + lg * 4)) ^ sz)) = w;
    }
  }
}

// Full 4-stage MLP for the wave's 64 samples via 2 half-passes (32 samples).
// Returns own-sample pre-activation (before +b4, tanh).
// stage1: sparse MFMA, A = [W1|b1] in slots (lg=0,e=0,1), B = [u;1] likewise;
//   with identical A/B slot->k maps the contraction is slot-wise, so
//   D[j,s] = W1[j]*u[s] + b1[j] regardless of the HW k-map. (validated R8)
// mid1/mid2: permuted k-map; B = lane's OWN tr dwords (zero cross-lane),
//   A = one b128 from fragment-contiguous LDS. C-init = bias. (validated R4-R8)
__device__ __forceinline__ float mlp_full(
    float u, const u32* __restrict__ W2lds, const u32* __restrict__ W3lds,
    const float* __restrict__ W1, const float* __restrict__ b1,
    const float* __restrict__ b2, const float* __restrict__ b3,
    const float* __restrict__ W4, int lm, int lg)
{
  const f32x4 zero = {0.f, 0.f, 0.f, 0.f};

  // stage-1 A-fragments (8 dwords, live whole MLP)
  u32 A1w[8];
#pragma unroll
  for(int jt = 0; jt < 8; ++jt){
    const int j = lm + 16 * jt;
    const u32 v = pk2(W1[j], b1[j]);
    A1w[jt] = (lg == 0) ? v : 0u;
  }

  float pre = 0.f;

#pragma unroll
  for(int p = 0; p < 2; ++p){
    const float us0 = __shfl(u, p * 32 + lm, 64);
    const float us1 = __shfl(u, p * 32 + 16 + lm, 64);
    const u32 bx0 = pk2(us0, 1.0f), bx1 = pk2(us1, 1.0f);
    uint4 bq0; bq0.x = (lg == 0) ? bx0 : 0u; bq0.y = 0u; bq0.z = 0u; bq0.w = 0u;
    uint4 bq1; bq1.x = (lg == 0) ? bx1 : 0u; bq1.y = 0u; bq1.z = 0u; bq1.w = 0u;
    const bf16x8 bv0 = __builtin_bit_cast(bf16x8, bq0);
    const bf16x8 bv1 = __builtin_bit_cast(bf16x8, bq1);

    // ---- stage1: sparse MFMAs -> tr1 (H1, permuted-k layout) ----
    u32 tr1[8][2][2];
#pragma unroll
    for(int jt = 0; jt < 8; ++jt){
      uint4 a4; a4.x = A1w[jt]; a4.y = 0u; a4.z = 0u; a4.w = 0u;
      const bf16x8 av = __builtin_bit_cast(bf16x8, a4);
      f32x4 d0 = __builtin_amdgcn_mfma_f32_16x16x32_bf16(av, bv0, zero, 0, 0, 0);
      f32x4 d1 = __builtin_amdgcn_mfma_f32_16x16x32_bf16(av, bv1, zero, 0, 0, 0);
      tr1[jt][0][0] = pk2(fmaxf(d0[0], 0.f), fmaxf(d0[1], 0.f));
      tr1[jt][0][1] = pk2(fmaxf(d0[2], 0.f), fmaxf(d0[3], 0.f));
      tr1[jt][1][0] = pk2(fmaxf(d1[0], 0.f), fmaxf(d1[1], 0.f));
      tr1[jt][1][1] = pk2(fmaxf(d1[2], 0.f), fmaxf(d1[3], 0.f));
    }

    // ---- mid1: A = W2 (1x b128), B = own tr1; C-init = b2 ----
    u32 tr2[8][2][2];
#pragma unroll
    for(int jt = 0; jt < 8; ++jt){
      const int j = lm + 16 * jt;
      const u32 sz = (u32)((j & 7) << 2);
      const u32* r = W2lds + j * 64;
      const float4 bb = *(const float4*)(b2 + jt * 16 + lg * 4);
      f32x4 a0 = {bb.x, bb.y, bb.z, bb.w};
      f32x4 a1 = a0;
#pragma unroll
      for(int kt = 0; kt < 4; ++kt){
        bf16x8 av = __builtin_bit_cast(bf16x8,
            *(const uint4*)(r + (((u32)(kt * 16 + lg * 4)) ^ sz)));
        uint4 q0; q0.x = tr1[2*kt][0][0]; q0.y = tr1[2*kt][0][1];
        q0.z = tr1[2*kt+1][0][0]; q0.w = tr1[2*kt+1][0][1];
        uint4 q1; q1.x = tr1[2*kt][1][0]; q1.y = tr1[2*kt][1][1];
        q1.z = tr1[2*kt+1][1][0]; q1.w = tr1[2*kt+1][1][1];
        a0 = __builtin_amdgcn_mfma_f32_16x16x32_bf16(av, __builtin_bit_cast(bf16x8, q0), a0, 0, 0, 0);
        a1 = __builtin_amdgcn_mfma_f32_16x16x32_bf16(av, __builtin_bit_cast(bf16x8, q1), a1, 0, 0, 0);
      }
      tr2[jt][0][0] = pk2(fmaxf(a0[0], 0.f), fmaxf(a0[1], 0.f));
      tr2[jt][0][1] = pk2(fmaxf(a0[2], 0.f), fmaxf(a0[3], 0.f));
      tr2[jt][1][0] = pk2(fmaxf(a1[0], 0.f), fmaxf(a1[1], 0.f));
      tr2[jt][1][1] = pk2(fmaxf(a1[2], 0.f), fmaxf(a1[3], 0.f));
    }

    // ---- mid2 + stage-4 fold: A = W3 (1x b128), B = own tr2; C-init = b3 ----
    float p0 = 0.f, p1 = 0.f;
#pragma unroll
    for(int jt = 0; jt < 8; ++jt){
      const int j = lm + 16 * jt;
      const u32 sz = (u32)((j & 7) << 2);
      const u32* r = W3lds + j * 64;
      const float4 bc = *(const float4*)(b3 + jt * 16 + lg * 4);
      f32x4 a0 = {bc.x, bc.y, bc.z, bc.w};
      f32x4 a1 = a0;
#pragma unroll
      for(int kt = 0; kt < 4; ++kt){
        bf16x8 av = __builtin_bit_cast(bf16x8,
            *(const uint4*)(r + (((u32)(kt * 16 + lg * 4)) ^ sz)));
        uint4 q0; q0.x = tr2[2*kt][0][0]; q0.y = tr2[2*kt][0][1];
        q0.z = tr2[2*kt+1][0][0]; q0.w = tr2[2*kt+1][0][1];
        uint4 q1; q1.x = tr2[2*kt][1][0]; q1.y = tr2[2*kt][1][1];
        q1.z = tr2[2*kt+1][1][0]; q1.w = tr2[2*kt+1][1][1];
        a0 = __builtin_amdgcn_mfma_f32_16x16x32_bf16(av, __builtin_bit_cast(bf16x8, q0), a0, 0, 0, 0);
        a1 = __builtin_amdgcn_mfma_f32_16x16x32_bf16(av, __builtin_bit_cast(bf16x8, q1), a1, 0, 0, 0);
      }
      const float4 wc = *(const float4*)(W4 + jt * 16 + lg * 4);
      p0 = fmaf(fmaxf(a0[0], 0.f), wc.x, p0);
      p0 = fmaf(fmaxf(a0[1], 0.f), wc.y, p0);
      p0 = fmaf(fmaxf(a0[2], 0.f), wc.z, p0);
      p0 = fmaf(fmaxf(a0[3], 0.f), wc.w, p0);
      p1 = fmaf(fmaxf(a1[0], 0.f), wc.x, p1);
      p1 = fmaf(fmaxf(a1[1], 0.f), wc.y, p1);
      p1 = fmaf(fmaxf(a1[2], 0.f), wc.z, p1);
      p1 = fmaf(fmaxf(a1[3], 0.f), wc.w, p1);
    }
    p0 += __shfl_xor(p0, 16, 64); p0 += __shfl_xor(p0, 32, 64);
    p1 += __shfl_xor(p1, 16, 64); p1 += __shfl_xor(p1, 32, 64);
    // own sample lane = lg*16+lm lives in pass p = lg>>1, sub-tile q = lg&1
    if((lg >> 1) == p) pre = ((lg & 1) == 0) ? p0 : p1;
  }
  return pre;
}

extern "C" __global__ void __launch_bounds__(BLK, 2)
flow_kernel(const float* __restrict__ x, const float* __restrict__ s_scale,
            const float* __restrict__ sW1, const float* __restrict__ sb1,
            const float* __restrict__ sW2, const float* __restrict__ sb2,
            const float* __restrict__ sW3, const float* __restrict__ sb3,
            const float* __restrict__ sW4, const float* __restrict__ sb4,
            const float* __restrict__ tW1, const float* __restrict__ tb1,
            const float* __restrict__ tW2, const float* __restrict__ tb2,
            const float* __restrict__ tW3, const float* __restrict__ tb3,
            const float* __restrict__ tW4, const float* __restrict__ tb4,
            float* __restrict__ out)
{
  __shared__ u32 Wlds[2][8192];   // 64 KB: W2 / W3 bf16, permuted + swizzled

  const int tid = threadIdx.x;
  const int lane = tid & 63, lg = lane >> 4, lm = lane & 15;
  const int gs = (int)blockIdx.x * BLK + tid;   // this thread's sample

  float2 ab = ((const float2*)x)[gs];
  float* scat = out + 2 * BATCH;

#pragma unroll 1
  for(int i = 0; i < LNUM; ++i){
    const int parity = i & 1;
    const float sc = s_scale[i];
    const int off = i * WD, offW = i * (WD * WD);

    // ---------- phase A: s-MLP ----------
    __syncthreads();                       // previous phase done reading Wlds
    stage_W(sW2 + offW, Wlds[0], tid);
    stage_W(sW3 + offW, Wlds[1], tid);
    __syncthreads();
    const float u = parity ? ab.y : ab.x;
    float preS = mlp_full(u, Wlds[0], Wlds[1], sW1 + off, sb1 + off,
                          sb2 + off, sb3 + off, sW4 + off, lm, lg) + sb4[i];
    const float sv = sc * tanhf(preS);
    scat[i * BATCH + gs] = sv;

    // ---------- phase B: t-MLP + coupling ----------
    __syncthreads();
    stage_W(tW2 + offW, Wlds[0], tid);
    stage_W(tW3 + offW, Wlds[1], tid);
    __syncthreads();
    float preT = mlp_full(u, Wlds[0], Wlds[1], tW1 + off, tb1 + off,
                          tb2 + off, tb3 + off, tW4 + off, lm, lg) + tb4[i];
    const float tv = tanhf(preT);
    const float e = expf(sv);
    if(parity) ab.x = e * ab.x + tv; else ab.y = e * ab.y + tv;
  }

  ((float2*)out)[gs] = ab;
}

extern "C" void kernel_launch(void* const* d_in, const int* in_sizes, int n_in,
                              void* d_out, int out_size, void* d_ws, size_t ws_size,
                              hipStream_t stream) {
  (void)in_sizes; (void)n_in; (void)d_ws; (void)ws_size; (void)out_size;
  const float* p[18];
  for(int k = 0; k < 18; ++k) p[k] = (const float*)d_in[k];
  dim3 grid(BATCH / BLK), block(BLK);
  hipLaunchKernelGGL(flow_kernel, grid, block, 0, stream,
                     p[0], p[1], p[2], p[3], p[4], p[5], p[6], p[7], p[8], p[9],
                     p[10], p[11], p[12], p[13], p[14], p[15], p[16], p[17],
                     (float*)d_out);
}

// Round 10
// 443.047 us; speedup vs baseline: 13.4905x; 2.4521x over previous
//
#include <hip/hip_runtime.h>

#define LNUM 8
#define WD 128
#define BATCH 262144
#define BLK 256

typedef unsigned int u32;
typedef __attribute__((ext_vector_type(8))) short bf16x8;
typedef __attribute__((ext_vector_type(4))) float f32x4;

// packed f32x2 -> bf16x2 (single VALU op; validated R4+)
__device__ __forceinline__ u32 pk2(float x, float y){
  u32 r;
  asm("v_cvt_pk_bf16_f32 %0, %1, %2" : "=v"(r) : "v"(x), "v"(y));
  return r;
}

__device__ __forceinline__ void fence(){ __builtin_amdgcn_sched_barrier(0); }

// NATURAL-order staging (W2, for mid1's natural k-map). Row-major bf16,
// XOR-swizzled at 4-dword granularity. Validated R2/R3.
// 256 threads: row j=t>>1, half h=t&1.
__device__ __forceinline__ void stage_Wnat(const float* __restrict__ src, u32* dst, int tid){
  const int j = tid >> 1, h = tid & 1;
  const float* s = src + j * WD + h * 64;
  u32* drow = dst + j * 64;
  const int base = h * 32;
  const u32 sz = (u32)((j & 7) << 2);
#pragma unroll
  for(int c = 0; c < 8; ++c){
    float4 f0 = *(const float4*)(s + c * 8);
    float4 f1 = *(const float4*)(s + c * 8 + 4);
    uint4 w;
    w.x = pk2(f0.x, f0.y); w.y = pk2(f0.z, f0.w);
    w.z = pk2(f1.x, f1.y); w.w = pk2(f1.z, f1.w);
    *(uint4*)(drow + (((u32)(base + c * 4)) ^ sz)) = w;
  }
}

// PERMUTED fragment-contiguous staging (W3, for mid2's permuted k-map
// slot(lg,e) <-> k = kt*32+(e>>2)*16+lg*4+(e&3)): the A-fragment for (lg,kt)
// is ONE b128 at dword (kt*16+lg*4)^sz. Validated R9.
__device__ __forceinline__ void stage_Wperm(const float* __restrict__ src, u32* dst, int tid){
  const int j = tid >> 1, h = tid & 1;
  const float* srow = src + j * WD;
  u32* drow = dst + j * 64;
  const u32 sz = (u32)((j & 7) << 2);
#pragma unroll
  for(int kk = 0; kk < 2; ++kk){
    const int kt = 2 * h + kk;
#pragma unroll
    for(int lg = 0; lg < 4; ++lg){
      float4 f0 = *(const float4*)(srow + kt * 32 + lg * 4);
      float4 f1 = *(const float4*)(srow + kt * 32 + 16 + lg * 4);
      uint4 w;
      w.x = pk2(f0.x, f0.y); w.y = pk2(f0.z, f0.w);
      w.z = pk2(f1.x, f1.y); w.w = pk2(f1.z, f1.w);
      *(uint4*)(drow + (((u32)(kt * 16 + lg * 4)) ^ sz)) = w;
    }
  }
}

// Full 4-stage MLP for the wave's 64 samples in ONE pass (R3's proven-clean
// allocation shape: kt-outer mid1 with transient bv[4], acc1[8][4] in the
// AGPR half, coarse sched fences between stages).
// mid1: natural k-map, A = b128 natural LDS (R3). C-init = b2 (R7+).
// mid2: permuted k-map, B = lane's OWN tr dwords (R4+), A = b128 from
//       fragment-contiguous LDS (R9). C-init = b3.
__device__ __forceinline__ float mlp_full(
    float u, const u32* __restrict__ W2lds, const u32* __restrict__ W3lds,
    const float* __restrict__ W1, const float* __restrict__ b1,
    const float* __restrict__ b2, const float* __restrict__ b3,
    const float* __restrict__ W4, int lm, int lg)
{
  float ust[4];
#pragma unroll
  for(int st = 0; st < 4; ++st) ust[st] = __shfl(u, st * 16 + lm, 64);

  // acc1 = b2 bias (MFMA C-input; m89 D-map row j = jt*16 + lg*4 + reg)
  f32x4 acc1[8][4];
#pragma unroll
  for(int jt = 0; jt < 8; ++jt){
    const float4 bb = *(const float4*)(b2 + jt * 16 + lg * 4);
    const f32x4 binit = {bb.x, bb.y, bb.z, bb.w};
#pragma unroll
    for(int st = 0; st < 4; ++st) acc1[jt][st] = binit;
  }

  // ---- stage1 (VALU, transient bv[4]) + mid1 (natural k-map, kt-outer) ----
#pragma unroll
  for(int kt = 0; kt < 4; ++kt){
    const int ko = kt * 32 + lg * 8;
    const float4 w1a = *(const float4*)(W1 + ko);
    const float4 w1b = *(const float4*)(W1 + ko + 4);
    const float4 g1a = *(const float4*)(b1 + ko);
    const float4 g1b = *(const float4*)(b1 + ko + 4);
    bf16x8 bv[4];
#pragma unroll
    for(int st = 0; st < 4; ++st){
      const float uv = ust[st];
      uint4 pk;
      pk.x = pk2(fmaxf(fmaf(uv, w1a.x, g1a.x), 0.f), fmaxf(fmaf(uv, w1a.y, g1a.y), 0.f));
      pk.y = pk2(fmaxf(fmaf(uv, w1a.z, g1a.z), 0.f), fmaxf(fmaf(uv, w1a.w, g1a.w), 0.f));
      pk.z = pk2(fmaxf(fmaf(uv, w1b.x, g1b.x), 0.f), fmaxf(fmaf(uv, w1b.y, g1b.y), 0.f));
      pk.w = pk2(fmaxf(fmaf(uv, w1b.z, g1b.z), 0.f), fmaxf(fmaf(uv, w1b.w, g1b.w), 0.f));
      bv[st] = __builtin_bit_cast(bf16x8, pk);
    }
    const u32 kdw = (u32)(kt * 16 + lg * 4);
#pragma unroll
    for(int jt = 0; jt < 8; ++jt){
      const int j = lm + 16 * jt;
      bf16x8 av = __builtin_bit_cast(bf16x8,
          *(const uint4*)(W2lds + j * 64 + (kdw ^ (u32)((j & 7) << 2))));
#pragma unroll
      for(int st = 0; st < 4; ++st)
        acc1[jt][st] = __builtin_amdgcn_mfma_f32_16x16x32_bf16(av, bv[st], acc1[jt][st], 0, 0, 0);
    }
  }
  fence();

  // ---- transition: relu + pack (bias already in acc via C-init) ----
  u32 tr[8][4][2];
#pragma unroll
  for(int jt = 0; jt < 8; ++jt)
#pragma unroll
    for(int st = 0; st < 4; ++st){
      tr[jt][st][0] = pk2(fmaxf(acc1[jt][st][0], 0.f), fmaxf(acc1[jt][st][1], 0.f));
      tr[jt][st][1] = pk2(fmaxf(acc1[jt][st][2], 0.f), fmaxf(acc1[jt][st][3], 0.f));
    }
  fence();

  // ---- mid2 (permuted k-map; B = own tr; A = 1x b128) + stage-4 fold ----
  float p0 = 0.f, p1 = 0.f, p2 = 0.f, p3 = 0.f;
#pragma unroll
  for(int jt = 0; jt < 8; ++jt){
    const int j = lm + 16 * jt;
    const u32 sz = (u32)((j & 7) << 2);
    const u32* r = W3lds + j * 64;
    const float4 bc = *(const float4*)(b3 + jt * 16 + lg * 4);
    const f32x4 cinit = {bc.x, bc.y, bc.z, bc.w};
    f32x4 a0 = cinit, a1 = cinit, a2 = cinit, a3 = cinit;
#pragma unroll
    for(int kt = 0; kt < 4; ++kt){
      bf16x8 av = __builtin_bit_cast(bf16x8,
          *(const uint4*)(r + (((u32)(kt * 16 + lg * 4)) ^ sz)));
      uint4 q0; q0.x = tr[2*kt][0][0]; q0.y = tr[2*kt][0][1];
      q0.z = tr[2*kt+1][0][0]; q0.w = tr[2*kt+1][0][1];
      uint4 q1; q1.x = tr[2*kt][1][0]; q1.y = tr[2*kt][1][1];
      q1.z = tr[2*kt+1][1][0]; q1.w = tr[2*kt+1][1][1];
      uint4 q2; q2.x = tr[2*kt][2][0]; q2.y = tr[2*kt][2][1];
      q2.z = tr[2*kt+1][2][0]; q2.w = tr[2*kt+1][2][1];
      uint4 q3; q3.x = tr[2*kt][3][0]; q3.y = tr[2*kt][3][1];
      q3.z = tr[2*kt+1][3][0]; q3.w = tr[2*kt+1][3][1];
      a0 = __builtin_amdgcn_mfma_f32_16x16x32_bf16(av, __builtin_bit_cast(bf16x8, q0), a0, 0, 0, 0);
      a1 = __builtin_amdgcn_mfma_f32_16x16x32_bf16(av, __builtin_bit_cast(bf16x8, q1), a1, 0, 0, 0);
      a2 = __builtin_amdgcn_mfma_f32_16x16x32_bf16(av, __builtin_bit_cast(bf16x8, q2), a2, 0, 0, 0);
      a3 = __builtin_amdgcn_mfma_f32_16x16x32_bf16(av, __builtin_bit_cast(bf16x8, q3), a3, 0, 0, 0);
    }
    const float4 wc = *(const float4*)(W4 + jt * 16 + lg * 4);
    p0 = fmaf(fmaxf(a0[0], 0.f), wc.x, p0); p0 = fmaf(fmaxf(a0[1], 0.f), wc.y, p0);
    p0 = fmaf(fmaxf(a0[2], 0.f), wc.z, p0); p0 = fmaf(fmaxf(a0[3], 0.f), wc.w, p0);
    p1 = fmaf(fmaxf(a1[0], 0.f), wc.x, p1); p1 = fmaf(fmaxf(a1[1], 0.f), wc.y, p1);
    p1 = fmaf(fmaxf(a1[2], 0.f), wc.z, p1); p1 = fmaf(fmaxf(a1[3], 0.f), wc.w, p1);
    p2 = fmaf(fmaxf(a2[0], 0.f), wc.x, p2); p2 = fmaf(fmaxf(a2[1], 0.f), wc.y, p2);
    p2 = fmaf(fmaxf(a2[2], 0.f), wc.z, p2); p2 = fmaf(fmaxf(a2[3], 0.f), wc.w, p2);
    p3 = fmaf(fmaxf(a3[0], 0.f), wc.x, p3); p3 = fmaf(fmaxf(a3[1], 0.f), wc.y, p3);
    p3 = fmaf(fmaxf(a3[2], 0.f), wc.z, p3); p3 = fmaf(fmaxf(a3[3], 0.f), wc.w, p3);
  }
  fence();
  p0 += __shfl_xor(p0, 16, 64); p0 += __shfl_xor(p0, 32, 64);
  p1 += __shfl_xor(p1, 16, 64); p1 += __shfl_xor(p1, 32, 64);
  p2 += __shfl_xor(p2, 16, 64); p2 += __shfl_xor(p2, 32, 64);
  p3 += __shfl_xor(p3, 16, 64); p3 += __shfl_xor(p3, 32, 64);
  // own sample lane = lg*16+lm -> st index == lg
  return (lg == 0) ? p0 : (lg == 1) ? p1 : (lg == 2) ? p2 : p3;
}

extern "C" __global__ void __launch_bounds__(BLK, 2)
flow_kernel(const float* __restrict__ x, const float* __restrict__ s_scale,
            const float* __restrict__ sW1, const float* __restrict__ sb1,
            const float* __restrict__ sW2, const float* __restrict__ sb2,
            const float* __restrict__ sW3, const float* __restrict__ sb3,
            const float* __restrict__ sW4, const float* __restrict__ sb4,
            const float* __restrict__ tW1, const float* __restrict__ tb1,
            const float* __restrict__ tW2, const float* __restrict__ tb2,
            const float* __restrict__ tW3, const float* __restrict__ tb3,
            const float* __restrict__ tW4, const float* __restrict__ tb4,
            float* __restrict__ out)
{
  __shared__ u32 Wlds[2][8192];   // 64 KB: W2 (natural) / W3 (permuted), swizzled

  const int tid = threadIdx.x;
  const int lane = tid & 63, lg = lane >> 4, lm = lane & 15;
  const int gs = (int)blockIdx.x * BLK + tid;   // this thread's sample

  float2 ab = ((const float2*)x)[gs];
  float* scat = out + 2 * BATCH;

#pragma unroll 1
  for(int i = 0; i < LNUM; ++i){
    const int parity = i & 1;
    const float sc = s_scale[i];
    const int off = i * WD, offW = i * (WD * WD);

    // ---------- phase A: s-MLP ----------
    __syncthreads();                       // previous phase done reading Wlds
    stage_Wnat (sW2 + offW, Wlds[0], tid);
    stage_Wperm(sW3 + offW, Wlds[1], tid);
    __syncthreads();
    const float u = parity ? ab.y : ab.x;
    float preS = mlp_full(u, Wlds[0], Wlds[1], sW1 + off, sb1 + off,
                          sb2 + off, sb3 + off, sW4 + off, lm, lg) + sb4[i];
    const float sv = sc * tanhf(preS);
    scat[i * BATCH + gs] = sv;

    // ---------- phase B: t-MLP + coupling ----------
    __syncthreads();
    stage_Wnat (tW2 + offW, Wlds[0], tid);
    stage_Wperm(tW3 + offW, Wlds[1], tid);
    __syncthreads();
    float preT = mlp_full(u, Wlds[0], Wlds[1], tW1 + off, tb1 + off,
                          tb2 + off, tb3 + off, tW4 + off, lm, lg) + tb4[i];
    const float tv = tanhf(preT);
    const float e = expf(sv);
    if(parity) ab.x = e * ab.x + tv; else ab.y = e * ab.y + tv;
  }

  ((float2*)out)[gs] = ab;
}

extern "C" void kernel_launch(void* const* d_in, const int* in_sizes, int n_in,
                              void* d_out, int out_size, void* d_ws, size_t ws_size,
                              hipStream_t stream) {
  (void)in_sizes; (void)n_in; (void)d_ws; (void)ws_size; (void)out_size;
  const float* p[18];
  for(int k = 0; k < 18; ++k) p[k] = (const float*)d_in[k];
  dim3 grid(BATCH / BLK), block(BLK);
  hipLaunchKernelGGL(flow_kernel, grid, block, 0, stream,
                     p[0], p[1], p[2], p[3], p[4], p[5], p[6], p[7], p[8], p[9],
                     p[10], p[11], p[12], p[13], p[14], p[15], p[16], p[17],
                     (float*)d_out);
}

// Round 11
// 270.825 us; speedup vs baseline: 22.0693x; 1.6359x over previous
//
#include <hip/hip_runtime.h>

#define LNUM 8
#define WD 128
#define BATCH 262144

typedef unsigned int u32;
typedef __attribute__((ext_vector_type(8))) short bf16x8;
typedef __attribute__((ext_vector_type(4))) float f32x4;

// packed f32x2 -> bf16x2 (single VALU op; validated R4+)
__device__ __forceinline__ u32 pk2(float x, float y){
  u32 r;
  asm("v_cvt_pk_bf16_f32 %0, %1, %2" : "=v"(r) : "v"(x), "v"(y));
  return r;
}

__device__ __forceinline__ void fence(){ __builtin_amdgcn_sched_barrier(0); }

// NATURAL-order W image (for mid1's natural k-map): row-major bf16,
// XOR-swizzled at 4-dword granularity. dst may be LDS or global (generic).
// 256 threads: row j=t>>1, half h=t&1. Validated R2/R3/R10.
__device__ __forceinline__ void stage_Wnat(const float* __restrict__ src, u32* dst, int tid){
  const int j = tid >> 1, h = tid & 1;
  const float* s = src + j * WD + h * 64;
  u32* drow = dst + j * 64;
  const int base = h * 32;
  const u32 sz = (u32)((j & 7) << 2);
#pragma unroll
  for(int c = 0; c < 8; ++c){
    float4 f0 = *(const float4*)(s + c * 8);
    float4 f1 = *(const float4*)(s + c * 8 + 4);
    uint4 w;
    w.x = pk2(f0.x, f0.y); w.y = pk2(f0.z, f0.w);
    w.z = pk2(f1.x, f1.y); w.w = pk2(f1.z, f1.w);
    *(uint4*)(drow + (((u32)(base + c * 4)) ^ sz)) = w;
  }
}

// PERMUTED fragment-contiguous W image (for mid2's permuted k-map
// slot(lg,e) <-> k = kt*32+(e>>2)*16+lg*4+(e&3)): A-fragment for (lg,kt) is
// ONE b128 at dword (kt*16+lg*4)^sz. Validated R9/R10.
__device__ __forceinline__ void stage_Wperm(const float* __restrict__ src, u32* dst, int tid){
  const int j = tid >> 1, h = tid & 1;
  const float* srow = src + j * WD;
  u32* drow = dst + j * 64;
  const u32 sz = (u32)((j & 7) << 2);
#pragma unroll
  for(int kk = 0; kk < 2; ++kk){
    const int kt = 2 * h + kk;
#pragma unroll
    for(int g = 0; g < 4; ++g){
      float4 f0 = *(const float4*)(srow + kt * 32 + g * 4);
      float4 f1 = *(const float4*)(srow + kt * 32 + 16 + g * 4);
      uint4 w;
      w.x = pk2(f0.x, f0.y); w.y = pk2(f0.z, f0.w);
      w.z = pk2(f1.x, f1.y); w.w = pk2(f1.z, f1.w);
      *(uint4*)(drow + (((u32)(kt * 16 + g * 4)) ^ sz)) = w;
    }
  }
}

// DMA a 16384-dword (two-matrix) slab from the preprocessed global image into
// LDS. global_load_lds: per-lane GLOBAL src, wave-uniform LDS base + lane*16.
__device__ __forceinline__ void stage_dma(const u32* __restrict__ g, u32* l, int wv, int lane){
#pragma unroll
  for(int it = 0; it < 8; ++it){
    const int o = wv * 2048 + it * 256;
    __builtin_amdgcn_global_load_lds(
        (const __attribute__((address_space(1))) u32*)(g + o + lane * 4),
        (__attribute__((address_space(3))) u32*)(l + o),
        16, 0, 0);
  }
}

// Full 4-stage MLP for the wave's 64 samples (R10's proven-clean shape,
// byte-identical numerics). mid1: natural k-map, A = b128 natural LDS,
// C-init = b2. mid2: permuted k-map, B = lane's OWN tr dwords, A = b128
// fragment-contiguous LDS, C-init = b3. Validated R10 (443 us, absmax .03125).
__device__ __forceinline__ float mlp_full(
    float u, const u32* __restrict__ W2lds, const u32* __restrict__ W3lds,
    const float* __restrict__ W1, const float* __restrict__ b1,
    const float* __restrict__ b2, const float* __restrict__ b3,
    const float* __restrict__ W4, int lm, int lg)
{
  float ust[4];
#pragma unroll
  for(int st = 0; st < 4; ++st) ust[st] = __shfl(u, st * 16 + lm, 64);

  f32x4 acc1[8][4];
#pragma unroll
  for(int jt = 0; jt < 8; ++jt){
    const float4 bb = *(const float4*)(b2 + jt * 16 + lg * 4);
    const f32x4 binit = {bb.x, bb.y, bb.z, bb.w};
#pragma unroll
    for(int st = 0; st < 4; ++st) acc1[jt][st] = binit;
  }

  // ---- stage1 (VALU, transient bv[4]) + mid1 (natural k-map, kt-outer) ----
#pragma unroll
  for(int kt = 0; kt < 4; ++kt){
    const int ko = kt * 32 + lg * 8;
    const float4 w1a = *(const float4*)(W1 + ko);
    const float4 w1b = *(const float4*)(W1 + ko + 4);
    const float4 g1a = *(const float4*)(b1 + ko);
    const float4 g1b = *(const float4*)(b1 + ko + 4);
    bf16x8 bv[4];
#pragma unroll
    for(int st = 0; st < 4; ++st){
      const float uv = ust[st];
      uint4 pk;
      pk.x = pk2(fmaxf(fmaf(uv, w1a.x, g1a.x), 0.f), fmaxf(fmaf(uv, w1a.y, g1a.y), 0.f));
      pk.y = pk2(fmaxf(fmaf(uv, w1a.z, g1a.z), 0.f), fmaxf(fmaf(uv, w1a.w, g1a.w), 0.f));
      pk.z = pk2(fmaxf(fmaf(uv, w1b.x, g1b.x), 0.f), fmaxf(fmaf(uv, w1b.y, g1b.y), 0.f));
      pk.w = pk2(fmaxf(fmaf(uv, w1b.z, g1b.z), 0.f), fmaxf(fmaf(uv, w1b.w, g1b.w), 0.f));
      bv[st] = __builtin_bit_cast(bf16x8, pk);
    }
    const u32 kdw = (u32)(kt * 16 + lg * 4);
#pragma unroll
    for(int jt = 0; jt < 8; ++jt){
      const int j = lm + 16 * jt;
      bf16x8 av = __builtin_bit_cast(bf16x8,
          *(const uint4*)(W2lds + j * 64 + (kdw ^ (u32)((j & 7) << 2))));
#pragma unroll
      for(int st = 0; st < 4; ++st)
        acc1[jt][st] = __builtin_amdgcn_mfma_f32_16x16x32_bf16(av, bv[st], acc1[jt][st], 0, 0, 0);
    }
  }
  fence();

  // ---- transition: relu + pack ----
  u32 tr[8][4][2];
#pragma unroll
  for(int jt = 0; jt < 8; ++jt)
#pragma unroll
    for(int st = 0; st < 4; ++st){
      tr[jt][st][0] = pk2(fmaxf(acc1[jt][st][0], 0.f), fmaxf(acc1[jt][st][1], 0.f));
      tr[jt][st][1] = pk2(fmaxf(acc1[jt][st][2], 0.f), fmaxf(acc1[jt][st][3], 0.f));
    }
  fence();

  // ---- mid2 (permuted k-map; B = own tr; A = 1x b128) + stage-4 fold ----
  float p0 = 0.f, p1 = 0.f, p2 = 0.f, p3 = 0.f;
#pragma unroll
  for(int jt = 0; jt < 8; ++jt){
    const int j = lm + 16 * jt;
    const u32 sz = (u32)((j & 7) << 2);
    const u32* r = W3lds + j * 64;
    const float4 bc = *(const float4*)(b3 + jt * 16 + lg * 4);
    const f32x4 cinit = {bc.x, bc.y, bc.z, bc.w};
    f32x4 a0 = cinit, a1 = cinit, a2 = cinit, a3 = cinit;
#pragma unroll
    for(int kt = 0; kt < 4; ++kt){
      bf16x8 av = __builtin_bit_cast(bf16x8,
          *(const uint4*)(r + (((u32)(kt * 16 + lg * 4)) ^ sz)));
      uint4 q0; q0.x = tr[2*kt][0][0]; q0.y = tr[2*kt][0][1];
      q0.z = tr[2*kt+1][0][0]; q0.w = tr[2*kt+1][0][1];
      uint4 q1; q1.x = tr[2*kt][1][0]; q1.y = tr[2*kt][1][1];
      q1.z = tr[2*kt+1][1][0]; q1.w = tr[2*kt+1][1][1];
      uint4 q2; q2.x = tr[2*kt][2][0]; q2.y = tr[2*kt][2][1];
      q2.z = tr[2*kt+1][2][0]; q2.w = tr[2*kt+1][2][1];
      uint4 q3; q3.x = tr[2*kt][3][0]; q3.y = tr[2*kt][3][1];
      q3.z = tr[2*kt+1][3][0]; q3.w = tr[2*kt+1][3][1];
      a0 = __builtin_amdgcn_mfma_f32_16x16x32_bf16(av, __builtin_bit_cast(bf16x8, q0), a0, 0, 0, 0);
      a1 = __builtin_amdgcn_mfma_f32_16x16x32_bf16(av, __builtin_bit_cast(bf16x8, q1), a1, 0, 0, 0);
      a2 = __builtin_amdgcn_mfma_f32_16x16x32_bf16(av, __builtin_bit_cast(bf16x8, q2), a2, 0, 0, 0);
      a3 = __builtin_amdgcn_mfma_f32_16x16x32_bf16(av, __builtin_bit_cast(bf16x8, q3), a3, 0, 0, 0);
    }
    const float4 wc = *(const float4*)(W4 + jt * 16 + lg * 4);
    p0 = fmaf(fmaxf(a0[0], 0.f), wc.x, p0); p0 = fmaf(fmaxf(a0[1], 0.f), wc.y, p0);
    p0 = fmaf(fmaxf(a0[2], 0.f), wc.z, p0); p0 = fmaf(fmaxf(a0[3], 0.f), wc.w, p0);
    p1 = fmaf(fmaxf(a1[0], 0.f), wc.x, p1); p1 = fmaf(fmaxf(a1[1], 0.f), wc.y, p1);
    p1 = fmaf(fmaxf(a1[2], 0.f), wc.z, p1); p1 = fmaf(fmaxf(a1[3], 0.f), wc.w, p1);
    p2 = fmaf(fmaxf(a2[0], 0.f), wc.x, p2); p2 = fmaf(fmaxf(a2[1], 0.f), wc.y, p2);
    p2 = fmaf(fmaxf(a2[2], 0.f), wc.z, p2); p2 = fmaf(fmaxf(a2[3], 0.f), wc.w, p2);
    p3 = fmaf(fmaxf(a3[0], 0.f), wc.x, p3); p3 = fmaf(fmaxf(a3[1], 0.f), wc.y, p3);
    p3 = fmaf(fmaxf(a3[2], 0.f), wc.z, p3); p3 = fmaf(fmaxf(a3[3], 0.f), wc.w, p3);
  }
  fence();
  p0 += __shfl_xor(p0, 16, 64); p0 += __shfl_xor(p0, 32, 64);
  p1 += __shfl_xor(p1, 16, 64); p1 += __shfl_xor(p1, 32, 64);
  p2 += __shfl_xor(p2, 16, 64); p2 += __shfl_xor(p2, 32, 64);
  p3 += __shfl_xor(p3, 16, 64); p3 += __shfl_xor(p3, 32, 64);
  return (lg == 0) ? p0 : (lg == 1) ? p1 : (lg == 2) ? p2 : p3;
}

// ---------------- preprocess: fp32 weights -> bf16 LDS-image in d_ws ----------------
// 32 blocks x 256 threads. Slab b (8192 dwords): layer = b>>2, which = b&3
// (0: sW2 natural, 1: sW3 permuted, 2: tW2 natural, 3: tW3 permuted).
extern "C" __global__ void __launch_bounds__(256)
prep_kernel(const float* __restrict__ sW2, const float* __restrict__ sW3,
            const float* __restrict__ tW2, const float* __restrict__ tW3,
            u32* __restrict__ ws)
{
  const int b = blockIdx.x;
  const int layer = b >> 2, which = b & 3;
  const float* src = (which == 0 ? sW2 : which == 1 ? sW3 : which == 2 ? tW2 : tW3)
                     + layer * (WD * WD);
  u32* dst = ws + b * 8192;
  if(which & 1) stage_Wperm(src, dst, threadIdx.x);
  else          stage_Wnat (src, dst, threadIdx.x);
}

// ---------------- main kernel: double-buffered DMA staging ----------------
extern "C" __global__ void __launch_bounds__(512)
flow_dma(const float* __restrict__ x, const float* __restrict__ s_scale,
         const float* __restrict__ sW1, const float* __restrict__ sb1,
         const float* __restrict__ sb2, const float* __restrict__ sb3,
         const float* __restrict__ sW4, const float* __restrict__ sb4,
         const float* __restrict__ tW1, const float* __restrict__ tb1,
         const float* __restrict__ tb2, const float* __restrict__ tb3,
         const float* __restrict__ tW4, const float* __restrict__ tb4,
         const u32* __restrict__ wimg, float* __restrict__ out)
{
  __shared__ u32 Wbuf[2][16384];   // 128 KB: [buf][W2(8192) | W3(8192)]

  const int tid = threadIdx.x;
  const int lane = tid & 63, lg = lane >> 4, lm = lane & 15, wv = tid >> 6;
  const int gs = (int)blockIdx.x * 512 + tid;

  float2 ab = ((const float2*)x)[gs];
  float* scat = out + 2 * BATCH;
  float sv = 0.f;

  stage_dma(wimg, Wbuf[0], wv, lane);          // phase 0 slab

#pragma unroll 1
  for(int ph = 0; ph < 2 * LNUM; ++ph){
    const int i = ph >> 1, isT = ph & 1, parity = i & 1;
    asm volatile("s_waitcnt vmcnt(0)" ::: "memory");
    __syncthreads();                            // Wbuf[ph&1] fully landed
    if(ph < 2 * LNUM - 1)
      stage_dma(wimg + (ph + 1) * 16384, Wbuf[(ph + 1) & 1], wv, lane);

    const int off = i * WD;
    const float u = parity ? ab.y : ab.x;
    const u32* W2l = Wbuf[ph & 1];
    const u32* W3l = Wbuf[ph & 1] + 8192;

    if(!isT){
      float pre = mlp_full(u, W2l, W3l, sW1 + off, sb1 + off,
                           sb2 + off, sb3 + off, sW4 + off, lm, lg) + sb4[i];
      sv = s_scale[i] * tanhf(pre);
      scat[i * BATCH + gs] = sv;
    } else {
      float pre = mlp_full(u, W2l, W3l, tW1 + off, tb1 + off,
                           tb2 + off, tb3 + off, tW4 + off, lm, lg) + tb4[i];
      const float tv = tanhf(pre);
      const float e = expf(sv);
      if(parity) ab.x = e * ab.x + tv; else ab.y = e * ab.y + tv;
    }
  }

  ((float2*)out)[gs] = ab;
}

// ---------------- fallback: R10 kernel verbatim (inline staging) ----------------
extern "C" __global__ void __launch_bounds__(256, 2)
flow_fb(const float* __restrict__ x, const float* __restrict__ s_scale,
        const float* __restrict__ sW1, const float* __restrict__ sb1,
        const float* __restrict__ sW2, const float* __restrict__ sb2,
        const float* __restrict__ sW3, const float* __restrict__ sb3,
        const float* __restrict__ sW4, const float* __restrict__ sb4,
        const float* __restrict__ tW1, const float* __restrict__ tb1,
        const float* __restrict__ tW2, const float* __restrict__ tb2,
        const float* __restrict__ tW3, const float* __restrict__ tb3,
        const float* __restrict__ tW4, const float* __restrict__ tb4,
        float* __restrict__ out)
{
  __shared__ u32 Wlds[2][8192];

  const int tid = threadIdx.x;
  const int lane = tid & 63, lg = lane >> 4, lm = lane & 15;
  const int gs = (int)blockIdx.x * 256 + tid;

  float2 ab = ((const float2*)x)[gs];
  float* scat = out + 2 * BATCH;

#pragma unroll 1
  for(int i = 0; i < LNUM; ++i){
    const int parity = i & 1;
    const float sc = s_scale[i];
    const int off = i * WD, offW = i * (WD * WD);

    __syncthreads();
    stage_Wnat (sW2 + offW, Wlds[0], tid);
    stage_Wperm(sW3 + offW, Wlds[1], tid);
    __syncthreads();
    const float u = parity ? ab.y : ab.x;
    float preS = mlp_full(u, Wlds[0], Wlds[1], sW1 + off, sb1 + off,
                          sb2 + off, sb3 + off, sW4 + off, lm, lg) + sb4[i];
    const float sv = sc * tanhf(preS);
    scat[i * BATCH + gs] = sv;

    __syncthreads();
    stage_Wnat (tW2 + offW, Wlds[0], tid);
    stage_Wperm(tW3 + offW, Wlds[1], tid);
    __syncthreads();
    float preT = mlp_full(u, Wlds[0], Wlds[1], tW1 + off, tb1 + off,
                          tb2 + off, tb3 + off, tW4 + off, lm, lg) + tb4[i];
    const float tv = tanhf(preT);
    const float e = expf(sv);
    if(parity) ab.x = e * ab.x + tv; else ab.y = e * ab.y + tv;
  }

  ((float2*)out)[gs] = ab;
}

extern "C" void kernel_launch(void* const* d_in, const int* in_sizes, int n_in,
                              void* d_out, int out_size, void* d_ws, size_t ws_size,
                              hipStream_t stream) {
  (void)in_sizes; (void)n_in; (void)out_size;
  const float* p[18];
  for(int k = 0; k < 18; ++k) p[k] = (const float*)d_in[k];

  const size_t need = (size_t)32 * 8192 * 4;   // 1 MiB bf16 weight image
  if(ws_size >= need){
    u32* ws = (u32*)d_ws;
    hipLaunchKernelGGL(prep_kernel, dim3(32), dim3(256), 0, stream,
                       p[4], p[6], p[12], p[14], ws);
    hipLaunchKernelGGL(flow_dma, dim3(BATCH / 512), dim3(512), 0, stream,
                       p[0], p[1], p[2], p[3], p[5], p[7], p[8], p[9],
                       p[10], p[11], p[13], p[15], p[16], p[17],
                       (const u32*)ws, (float*)d_out);
  } else {
    hipLaunchKernelGGL(flow_fb, dim3(BATCH / 256), dim3(256), 0, stream,
                       p[0], p[1], p[2], p[3], p[4], p[5], p[6], p[7], p[8], p[9],
                       p[10], p[11], p[12], p[13], p[14], p[15], p[16], p[17],
                       (float*)d_out);
  }
}